// Round 7
// baseline (320.579 us; speedup 1.0000x reference)
//
#include <hip/hip_runtime.h>
#include <stdint.h>

// Problem: B=4, T=4096, C=1024, H=16, HD=64, NBLOCKS=32, BSIZE=128
#define Bb   4
#define Tt   4096
#define Cc   1024
#define Hh   16
#define HDd  64
#define NBn  32
#define BSs  128
#define MTOT (Bb*Tt)   // 16384 rows

typedef short s16;
typedef __attribute__((ext_vector_type(8))) short  short8;   // 8 bf16 (4 VGPRs)
typedef __attribute__((ext_vector_type(4))) float  f32x4;    // MFMA C/D frag
typedef __attribute__((ext_vector_type(4))) int    int4v;

__device__ __forceinline__ s16 f2bf(float f) {   // f32 -> bf16, RNE
  union { float f; uint32_t u; } c; c.f = f;
  return (s16)((c.u + 0x7fffu + ((c.u >> 16) & 1u)) >> 16);
}

typedef const __attribute__((address_space(1))) void* gas_p;
typedef __attribute__((address_space(3))) void*       las_p;
__device__ __forceinline__ void lds16(const void* g, void* l) {
  // async global->LDS; LDS dest must be wave-uniform (HW adds lane*16)
  __builtin_amdgcn_global_load_lds((gas_p)g, (las_p)l, 16, 0, 0);
}

// ---------------- f32 -> bf16 conversion kernels ----------------
__global__ __launch_bounds__(256) void cvt_x(const float* __restrict__ in, s16* __restrict__ out) {
  int i = blockIdx.x * 256 + threadIdx.x;
  const f32x4* p = (const f32x4*)(in + (size_t)i * 8);
  f32x4 a = p[0], b = p[1];
  short8 o;
  o[0]=f2bf(a[0]); o[1]=f2bf(a[1]); o[2]=f2bf(a[2]); o[3]=f2bf(a[3]);
  o[4]=f2bf(b[0]); o[5]=f2bf(b[1]); o[6]=f2bf(b[2]); o[7]=f2bf(b[3]);
  *(short8*)(out + (size_t)i * 8) = o;
}

__global__ __launch_bounds__(256) void cvt_w(const float* w0, const float* w1,
                                             const float* w2, const float* w3,
                                             s16* o0, s16* o1, s16* o2, s16* o3) {
  int i = blockIdx.x * 256 + threadIdx.x;
  int which = i >> 17;
  int j = i & 131071;
  const float* w = which == 0 ? w0 : which == 1 ? w1 : which == 2 ? w2 : w3;
  s16*         o = which == 0 ? o0 : which == 1 ? o1 : which == 2 ? o2 : o3;
  const f32x4* p = (const f32x4*)(w + (size_t)j * 8);
  f32x4 a = p[0], b = p[1];
  short8 v;
  v[0]=f2bf(a[0]); v[1]=f2bf(a[1]); v[2]=f2bf(a[2]); v[3]=f2bf(a[3]);
  v[4]=f2bf(b[0]); v[5]=f2bf(b[1]); v[6]=f2bf(b[2]); v[7]=f2bf(b[3]);
  *(short8*)(o + (size_t)j * 8) = v;
}

// ---------------- 256x256 pipelined bt-GEMM: C[m,n] = sum_k A[m,k]*W[n,k] (+bias) ----
// 8 waves (2m x 4n), per-wave 128x64 out = 8x4 16x16 frags. BK=64, K=1024 (16 K-tiles),
// 2-slot LDS double buffer (128 KiB). m201-style 4-phase schedule with counted vmcnt:
//
// Half-tiles of a K-tile (each 16 KB = 2 global_load_lds/thread, rounds j=0,1):
//   h0=B rows 0-127, h1=B rows 128-255, h2=A rows 0-127, h3=A rows 128-255.
// During K-tile kt, phase p issues half-tile h=p of K-tile kt+1 into slot c^1.
//
// Read alignment (why counted waits are provably safe, using FIFO vmcnt retirement):
//   wm waves read ONLY their A-half (wm=0->h2, wm=1->h3); phase p reads A rows
//   [wmBase + p*32, +32). wn waves read ONLY their B-half (wn<2->h0, wn>=2->h1),
//   all at phase 0. Per-thread issue order: B0j0,B0j1,B1j0,B1j1,A0j0,A0j1,A1j0,A1j1.
//   - vmcnt(1) at kt p3 (then barrier): 7 oldest landed = everything through A1j0
//     of tile kt+1 -> kt+1 p0/p1 reads (B all, A rows p*32 incl. 128-191) safe.
//   - vmcnt(4) at kt p1 (then barrier): outstanding <= {A1j1(kt), B0ab,B1ab(kt+1)}
//     -> A1j1 of tile kt landed -> kt p2/p3 reads (A rows 192-255) safe.
//     (kt==15 issues nothing, so use vmcnt(0) there to pin A1j1(t15).)
// Queue never drains in steady state: 1-5 loads in flight across every barrier.
// LDS element (row,k) lives at [row*64 + ((k>>3)^(row&7))*8 + (k&7)] (XOR swizzle
// applied on the global src; measured 0 bank conflicts r6).
template <bool OUT_BF16, int NXT>
__global__ __launch_bounds__(512, 2) void gemm256(const s16* __restrict__ Ag, const s16* __restrict__ Bg,
                                                  const float* b0, const float* b1, const float* b2,
                                                  void* o0, void* o1, void* o2) {
  __shared__ s16 smem[65536];   // 128 KiB: As[2][256][64] | Bs[2][256][64]

  const int tid = threadIdx.x;
  const int w = tid >> 6, l = tid & 63;
  const int lr = l & 15, lk = l >> 4;
  const int wm = w >> 2, wn = w & 3;

  // XCD-chunked block swizzle: xcd owns 8 m-tiles x NXT n-tiles (grid = 8*8*NXT)
  const int lid = blockIdx.x;
  const int xcd = lid & 7, s0 = lid >> 3;
  const int my = xcd * 8 + s0 / NXT;
  const int nx = s0 - (s0 / NXT) * NXT;
  const int mBase = my * 256, nBase = nx * 256;

  f32x4 acc[8][4];
#pragma unroll
  for (int i = 0; i < 8; ++i)
#pragma unroll
    for (int j = 0; j < 4; ++j) acc[i][j] = (f32x4){0.f, 0.f, 0.f, 0.f};

  // ---- half-tile stage: h in {0:B0,1:B1,2:A0,3:A1}; 2 loads/thread, FIFO j order ----
  auto stage_half = [&](int slot, int k0, int h) {
    const bool isA = (h >= 2);
    const int rbase = (h & 1) << 7;                 // 0 or 128
    const s16* src = isA ? Ag : Bg;
    const int gB = (isA ? mBase : nBase) + rbase;
    s16* dsth = smem + (isA ? 0 : 32768) + slot * 16384 + rbase * 64;
#pragma unroll
    for (int j = 0; j < 2; ++j) {
      int s = j * 512 + tid;
      int r = s >> 3;                               // 0..127 local
      int kg = (s & 7) ^ (r & 7);
      lds16(src + (size_t)(gB + r) * Cc + (k0 + kg * 8),
            dsth + (j * 512 + (tid & ~63)) * 8);    // wave-uniform LDS dest
    }
  };

  // prologue: tile 0 -> slot 0; keep A1j1 in flight (matches steady state)
  stage_half(0, 0, 0); stage_half(0, 0, 1); stage_half(0, 0, 2); stage_half(0, 0, 3);
  asm volatile("s_waitcnt vmcnt(1)" ::: "memory");
  __syncthreads();

  for (int kt = 0; kt < 16; ++kt) {
    const int c = kt & 1;
    const s16* Asc = smem + c * 16384;
    const s16* Bsc = smem + 32768 + c * 16384;
    short8 bk[4][2];                                // B-frags live across all 4 phases
#pragma unroll
    for (int p = 0; p < 4; ++p) {
      if (p == 0) {
#pragma unroll
        for (int nt = 0; nt < 4; ++nt)
#pragma unroll
          for (int kk = 0; kk < 2; ++kk) {
            int row = wn * 64 + nt * 16 + lr;
            bk[nt][kk] = *(const short8*)&Bsc[row * 64 + (((kk * 4 + lk) ^ (row & 7)) * 8)];
          }
      }
      short8 af[2][2];
#pragma unroll
      for (int mt2 = 0; mt2 < 2; ++mt2)
#pragma unroll
        for (int kk = 0; kk < 2; ++kk) {
          int row = wm * 128 + (p * 2 + mt2) * 16 + lr;
          af[mt2][kk] = *(const short8*)&Asc[row * 64 + (((kk * 4 + lk) ^ (row & 7)) * 8)];
        }
      if (kt < 15) stage_half(c ^ 1, (kt + 1) * 64, p);
      if (p == 1) {
        if (kt < 15) asm volatile("s_waitcnt vmcnt(4)" ::: "memory");
        else         asm volatile("s_waitcnt vmcnt(0)" ::: "memory");
      }
      if (p == 3)    asm volatile("s_waitcnt vmcnt(1)" ::: "memory");
      __builtin_amdgcn_s_barrier();
      asm volatile("s_waitcnt lgkmcnt(0)" ::: "memory");
      __builtin_amdgcn_sched_barrier(0);
      __builtin_amdgcn_s_setprio(1);
#pragma unroll
      for (int mt2 = 0; mt2 < 2; ++mt2)
#pragma unroll
        for (int nt = 0; nt < 4; ++nt)
#pragma unroll
          for (int kk = 0; kk < 2; ++kk)
            acc[p * 2 + mt2][nt] = __builtin_amdgcn_mfma_f32_16x16x32_bf16(
                af[mt2][kk], bk[nt][kk], acc[p * 2 + mt2][nt], 0, 0, 0);
      __builtin_amdgcn_s_setprio(0);
      __builtin_amdgcn_s_barrier();
    }
  }

  if (OUT_BF16) {
    // segmented (Q|K|V by nBase>>10; 256-tile never straddles a 1024 boundary),
    // LDS-staged coalesced bf16 stores; two row-half passes (Cs = [128][264])
    const int seg = nBase >> 10;
    const float* bias = seg == 0 ? b0 : (seg == 1 ? b1 : b2);
    s16* outp = (s16*)(seg == 0 ? o0 : (seg == 1 ? o1 : o2));
    const int colL = nBase & 1023;
    s16* Cs = smem;
#pragma unroll
    for (int h = 0; h < 2; ++h) {
      if (wm == h) {
#pragma unroll
        for (int nt = 0; nt < 4; ++nt) {
          int col = wn * 64 + nt * 16 + lr;
          float bb = bias ? bias[colL + col] : 0.0f;
#pragma unroll
          for (int mt = 0; mt < 8; ++mt) {
            int r0 = mt * 16 + lk * 4;
#pragma unroll
            for (int i = 0; i < 4; ++i)
              Cs[(r0 + i) * 264 + col] = f2bf(acc[mt][nt][i] + bb);
          }
        }
      }
      __syncthreads();
      // 128 rows x 256 cols = 4096 short8 slots -> 8 iters of 512 threads
#pragma unroll
      for (int t = 0; t < 8; ++t) {
        int s2 = t * 512 + tid;
        int r = s2 >> 5, g = s2 & 31;
        *(short8*)&outp[(size_t)(mBase + h * 128 + r) * 1024 + colL + g * 8] =
            *(const short8*)&Cs[r * 264 + g * 8];
      }
      __syncthreads();
    }
  } else {
    // f32 direct store (16 lanes x 4 B consecutive = full lines)
    float* outp = (float*)o0;
#pragma unroll
    for (int nt = 0; nt < 4; ++nt) {
      int col = nBase + wn * 64 + nt * 16 + lr;
      float bb = b0[col];
#pragma unroll
      for (int mt = 0; mt < 8; ++mt) {
        int row0 = mBase + wm * 128 + mt * 16 + lk * 4;
#pragma unroll
        for (int i = 0; i < 4; ++i)
          outp[(size_t)(row0 + i) * 1024 + col] = acc[mt][nt][i] + bb;
      }
    }
  }
}

// ---------------- blockwise attention: one workgroup per (b, block, head) ----------------
// qs/ks [128][72] bf16; V stored TRANSPOSED vsT[d][j] (ld=136) with j-group XOR swizzle
// jg ^= (d&7)^(d>>3) -> staging scalar writes ~2-way free, PV B-frags are ds_read_b128.
// Softmax fully in-register (row = 16-lane lr group: 4x shfl_xor); P bf16 overlays qs/ks.
__global__ __launch_bounds__(256) void attn_kernel(const s16* __restrict__ Q, const s16* __restrict__ K,
                                                   const s16* __restrict__ V, s16* __restrict__ O) {
  __shared__ s16   u_qkp[19456];       // qs[128][72] | ks[128][72]; later P[128][152]
  __shared__ s16   vsT[64 * 136];      // 17408 B
  __shared__ float invSum[128];

  const int tid = threadIdx.x;
  const int w = tid >> 6, l = tid & 63;
  const int lr = l & 15, lk = l >> 4;
  const int bid = blockIdx.x;                       // b*512 + n*16 + h
  const int b = bid >> 9;
  const int n = (bid >> 4) & 31;
  const int h = bid & 15;
  const size_t tokBase = (size_t)b * Tt + (size_t)n * BSs;
  const int colBase = h * HDd;

  s16* qs = u_qkp;
  s16* ks = u_qkp + 9216;
  s16* P  = u_qkp;                                  // [128][152]

  // stage Q,K row-major; V transposed+swizzled
#pragma unroll
  for (int t = 0; t < 4; ++t) {
    int s = t * 256 + tid;
    int r = s >> 3, g = s & 7;
    size_t gidx = (tokBase + r) * Cc + colBase + g * 8;
    int4v  dq = *(const int4v*)&Q[gidx];
    int4v  dk = *(const int4v*)&K[gidx];
    short8 dv = *(const short8*)&V[gidx];
    *(int4v*)&qs[r * 72 + g * 8] = dq;
    *(int4v*)&ks[r * 72 + g * 8] = dk;
    int rg = r >> 3, rl = r & 7;
#pragma unroll
    for (int e = 0; e < 8; ++e) {
      int d = g * 8 + e;                            // d&7 == e, d>>3 == g
      vsT[d * 136 + ((rg ^ e ^ g) << 3) + rl] = dv[e];
    }
  }
  __syncthreads();

  // QK^T: wave w owns 32 query rows x 128 key cols = 2x8 16x16 tiles
  f32x4 accS[2][8];
#pragma unroll
  for (int mt = 0; mt < 2; ++mt)
#pragma unroll
    for (int nt = 0; nt < 8; ++nt) accS[mt][nt] = (f32x4){0.f, 0.f, 0.f, 0.f};

#pragma unroll
  for (int st = 0; st < 2; ++st) {
    short8 aq[2], bk[8];
#pragma unroll
    for (int mt = 0; mt < 2; ++mt)
      aq[mt] = *(const short8*)&qs[(w * 32 + mt * 16 + lr) * 72 + st * 32 + lk * 8];
#pragma unroll
    for (int nt = 0; nt < 8; ++nt)
      bk[nt] = *(const short8*)&ks[(nt * 16 + lr) * 72 + st * 32 + lk * 8];
#pragma unroll
    for (int mt = 0; mt < 2; ++mt)
#pragma unroll
      for (int nt = 0; nt < 8; ++nt)
        accS[mt][nt] = __builtin_amdgcn_mfma_f32_16x16x32_bf16(aq[mt], bk[nt], accS[mt][nt], 0, 0, 0);
  }

  // in-register softmax: row (w,mt,lk,i) spread across 16 lanes (lr) x 8 frags (nt).
  // logits = raw/8 -> p = exp((raw - rawmax) * 0.125)
#pragma unroll
  for (int mt = 0; mt < 2; ++mt)
#pragma unroll
    for (int i = 0; i < 4; ++i) {
      float m = accS[mt][0][i];
#pragma unroll
      for (int nt = 1; nt < 8; ++nt) m = fmaxf(m, accS[mt][nt][i]);
      m = fmaxf(m, __shfl_xor(m, 1));
      m = fmaxf(m, __shfl_xor(m, 2));
      m = fmaxf(m, __shfl_xor(m, 4));
      m = fmaxf(m, __shfl_xor(m, 8));
      float sum = 0.f;
#pragma unroll
      for (int nt = 0; nt < 8; ++nt) {
        float p = __expf((accS[mt][nt][i] - m) * 0.125f);
        sum += p;
        accS[mt][nt][i] = p;
      }
      sum += __shfl_xor(sum, 1);
      sum += __shfl_xor(sum, 2);
      sum += __shfl_xor(sum, 4);
      sum += __shfl_xor(sum, 8);
      if (lr == 0) invSum[w * 32 + mt * 16 + lk * 4 + i] = 1.0f / sum;
    }
  __syncthreads();   // all waves done reading qs/ks before P overwrites them

  // P (unnormalized exp) -> LDS bf16
#pragma unroll
  for (int mt = 0; mt < 2; ++mt)
#pragma unroll
    for (int nt = 0; nt < 8; ++nt)
#pragma unroll
      for (int i = 0; i < 4; ++i)
        P[(w * 32 + mt * 16 + lk * 4 + i) * 152 + nt * 16 + lr] = f2bf(accS[mt][nt][i]);
  __syncthreads();

  // O = P * V: all-vector LDS reads now (A from P rows, B from vsT)
  f32x4 accO[2][4];
#pragma unroll
  for (int mt = 0; mt < 2; ++mt)
#pragma unroll
    for (int nt = 0; nt < 4; ++nt) accO[mt][nt] = (f32x4){0.f, 0.f, 0.f, 0.f};

#pragma unroll
  for (int st = 0; st < 4; ++st) {
    short8 ap[2], bv[4];
#pragma unroll
    for (int mt = 0; mt < 2; ++mt)
      ap[mt] = *(const short8*)&P[(w * 32 + mt * 16 + lr) * 152 + st * 32 + lk * 8];
#pragma unroll
    for (int nt = 0; nt < 4; ++nt) {
      int d = nt * 16 + lr;
      bv[nt] = *(const short8*)&vsT[d * 136 + ((((st * 4 + lk) ^ (d & 7) ^ (d >> 3))) << 3)];
    }
#pragma unroll
    for (int mt = 0; mt < 2; ++mt)
#pragma unroll
      for (int nt = 0; nt < 4; ++nt)
        accO[mt][nt] = __builtin_amdgcn_mfma_f32_16x16x32_bf16(ap[mt], bv[nt], accO[mt][nt], 0, 0, 0);
  }

#pragma unroll
  for (int mt = 0; mt < 2; ++mt)
#pragma unroll
    for (int nt = 0; nt < 4; ++nt)
#pragma unroll
      for (int i = 0; i < 4; ++i) {
        int rl = w * 32 + mt * 16 + lk * 4 + i;
        int d = nt * 16 + lr;
        float v = accO[mt][nt][i] * invSum[rl];
        O[(tokBase + rl) * Cc + colBase + d] = f2bf(v);
      }
}

// ---------------- host ----------------
extern "C" void kernel_launch(void* const* d_in, const int* in_sizes, int n_in,
                              void* d_out, int out_size, void* d_ws, size_t ws_size,
                              hipStream_t stream) {
  const float* x  = (const float*)d_in[0];
  const float* Wq = (const float*)d_in[1];
  const float* bq = (const float*)d_in[2];
  const float* Wk = (const float*)d_in[3];
  const float* Wv = (const float*)d_in[4];
  const float* bv = (const float*)d_in[5];
  const float* Wo = (const float*)d_in[6];
  const float* bo = (const float*)d_in[7];

  // ws layout (72 MB): xb 32M | wq|wk|wv (6M contiguous = fused 3072x1024) | wo 2M | Qb 32M.
  // K/V bf16 live in d_out (64 MB), consumed by attn before the final GEMM overwrites it.
  if (ws_size < (size_t)75497472) return;
  char* ws = (char*)d_ws;
  s16* xb  = (s16*)(ws);
  s16* wqb = (s16*)(ws + 33554432);
  s16* wkb = (s16*)(ws + 35651584);
  s16* wvb = (s16*)(ws + 37748736);
  s16* wob = (s16*)(ws + 39845888);
  s16* Qb  = (s16*)(ws + 41943040);
  s16* Kb  = (s16*)((char*)d_out);
  s16* Vb  = (s16*)((char*)d_out + 33554432);

  // 1) convert inputs to bf16
  cvt_x<<<8192, 256, 0, stream>>>(x, xb);
  cvt_w<<<2048, 256, 0, stream>>>(Wq, Wk, Wv, Wo, wqb, wkb, wvb, wob);

  // 2) fused QKV projection: [16384x1024] x [3072x1024]^T -> Qb|Kb|Vb (segmented)
  gemm256<true, 12><<<8 * 8 * 12, 512, 0, stream>>>(xb, wqb, bq, nullptr, bv, Qb, Kb, Vb);

  // 3) blockwise attention; O overwrites Qb (block-disjoint, Q staged to LDS first)
  attn_kernel<<<Bb * NBn * Hh, 256, 0, stream>>>(Qb, Kb, Vb, Qb);

  // 4) out = O Wo^T + bo (f32), overwrites K/V scratch in d_out
  gemm256<false, 4><<<8 * 8 * 4, 512, 0, stream>>>(Qb, wob, bo, bo, bo, (float*)d_out, nullptr, nullptr);
}

// Round 9
// 313.200 us; speedup vs baseline: 1.0236x; 1.0236x over previous
//
#include <hip/hip_runtime.h>
#include <stdint.h>

// Problem: B=4, T=4096, C=1024, H=16, HD=64, NBLOCKS=32, BSIZE=128
#define Bb   4
#define Tt   4096
#define Cc   1024
#define Hh   16
#define HDd  64
#define NBn  32
#define BSs  128
#define MTOT (Bb*Tt)   // 16384 rows

typedef short s16;
typedef __attribute__((ext_vector_type(8))) short  short8;   // 8 bf16 (4 VGPRs)
typedef __attribute__((ext_vector_type(4))) float  f32x4;    // MFMA C/D frag
typedef __attribute__((ext_vector_type(4))) int    int4v;

__device__ __forceinline__ s16 f2bf(float f) {   // f32 -> bf16, RNE
  union { float f; uint32_t u; } c; c.f = f;
  return (s16)((c.u + 0x7fffu + ((c.u >> 16) & 1u)) >> 16);
}

typedef const __attribute__((address_space(1))) void* gas_p;
typedef __attribute__((address_space(3))) void*       las_p;
__device__ __forceinline__ void lds16(const void* g, void* l) {
  // async global->LDS; LDS dest must be wave-uniform (HW adds lane*16)
  __builtin_amdgcn_global_load_lds((gas_p)g, (las_p)l, 16, 0, 0);
}

// ---------------- f32 -> bf16 conversion kernels ----------------
__global__ __launch_bounds__(256) void cvt_x(const float* __restrict__ in, s16* __restrict__ out) {
  int i = blockIdx.x * 256 + threadIdx.x;
  const f32x4* p = (const f32x4*)(in + (size_t)i * 8);
  f32x4 a = p[0], b = p[1];
  short8 o;
  o[0]=f2bf(a[0]); o[1]=f2bf(a[1]); o[2]=f2bf(a[2]); o[3]=f2bf(a[3]);
  o[4]=f2bf(b[0]); o[5]=f2bf(b[1]); o[6]=f2bf(b[2]); o[7]=f2bf(b[3]);
  *(short8*)(out + (size_t)i * 8) = o;
}

__global__ __launch_bounds__(256) void cvt_w(const float* w0, const float* w1,
                                             const float* w2, const float* w3,
                                             s16* o0, s16* o1, s16* o2, s16* o3) {
  int i = blockIdx.x * 256 + threadIdx.x;
  int which = i >> 17;
  int j = i & 131071;
  const float* w = which == 0 ? w0 : which == 1 ? w1 : which == 2 ? w2 : w3;
  s16*         o = which == 0 ? o0 : which == 1 ? o1 : which == 2 ? o2 : o3;
  const f32x4* p = (const f32x4*)(w + (size_t)j * 8);
  f32x4 a = p[0], b = p[1];
  short8 v;
  v[0]=f2bf(a[0]); v[1]=f2bf(a[1]); v[2]=f2bf(a[2]); v[3]=f2bf(a[3]);
  v[4]=f2bf(b[0]); v[5]=f2bf(b[1]); v[6]=f2bf(b[2]); v[7]=f2bf(b[3]);
  *(short8*)(o + (size_t)j * 8) = v;
}

// ---------------- 256x256 bt-GEMM: C[m,n] = sum_k A[m,k]*W[n,k] (+bias) ----------------
// 8 waves (2m x 4n), per-wave 128x64 out = 8x4 16x16 frags. BK=64, K=1024 (16 K-tiles),
// 2-slot LDS double buffer (128 KiB). ONE barrier per K-tile:
//   tile kt: issue all 8 global_load_lds of kt+1 into slot c^1 (first), read B-frags,
//   then 4 MFMA quadrants software-pipelined with next-quadrant A-frag ds_reads
//   (2-deep static A buffer), finally {s_waitcnt lgkmcnt(0) vmcnt(0); s_barrier}.
// Safety: stage writes slot c^1, all reads hit slot c. The explicit lgkmcnt(0)
// before the barrier guarantees BY CONSTRUCTION that each wave's ds_reads of slot c
// have retired before it crosses (rule #18: don't rely on the compiler keeping the
// consuming MFMAs ahead of an asm barrier). vmcnt(0) before the barrier -> on exit
// ALL waves' kt+1 loads have landed. The drain is issued a full tile (~4 quadrant
// phases) after the loads -> HBM latency covered.
// LDS element (row,k) lives at [row*64 + ((k>>3)^(row&7))*8 + (k&7)] (XOR swizzle
// applied on the global src; measured 0 bank conflicts r6/r7).
template <bool OUT_BF16, int NXT>
__global__ __launch_bounds__(512, 2) void gemm256(const s16* __restrict__ Ag, const s16* __restrict__ Bg,
                                                  const float* b0, const float* b1, const float* b2,
                                                  void* o0, void* o1, void* o2) {
  __shared__ s16 smem[65536];   // 128 KiB: As[2][256][64] | Bs[2][256][64]

  const int tid = threadIdx.x;
  const int w = tid >> 6, l = tid & 63;
  const int lr = l & 15, lk = l >> 4;
  const int wm = w >> 2, wn = w & 3;

  // XCD-chunked block swizzle: xcd owns 8 m-tiles x NXT n-tiles (grid = 8*8*NXT)
  const int lid = blockIdx.x;
  const int xcd = lid & 7, s0 = lid >> 3;
  const int my = xcd * 8 + s0 / NXT;
  const int nx = s0 - (s0 / NXT) * NXT;
  const int mBase = my * 256, nBase = nx * 256;

  f32x4 acc[8][4];
#pragma unroll
  for (int i = 0; i < 8; ++i)
#pragma unroll
    for (int j = 0; j < 4; ++j) acc[i][j] = (f32x4){0.f, 0.f, 0.f, 0.f};

  // ---- staging: 8 global_load_lds (4 A + 4 B), 512 lanes x 16 B each ----
  auto stage_tile = [&](int slot, int k0) {
    s16* Asl = smem + slot * 16384;
    s16* Bsl = smem + 32768 + slot * 16384;
#pragma unroll
    for (int L = 0; L < 4; ++L) {
      int s = L * 512 + tid;
      int r = s >> 3;
      int kg = (s & 7) ^ (r & 7);
      int wbase = (L * 512 + (tid & ~63)) * 8;   // wave-uniform LDS dest
      lds16(Ag + (size_t)(mBase + r) * Cc + (k0 + kg * 8), Asl + wbase);
      lds16(Bg + (size_t)(nBase + r) * Cc + (k0 + kg * 8), Bsl + wbase);
    }
  };

  // prologue: K-tile 0 -> slot 0
  stage_tile(0, 0);
  asm volatile("s_waitcnt vmcnt(0)" ::: "memory");
  __syncthreads();

  for (int kt = 0; kt < 16; ++kt) {
    const int c = kt & 1;
    const s16* Asc = smem + c * 16384;
    const s16* Bsc = smem + 32768 + c * 16384;

    // issue next-tile prefetch FIRST (T3 recipe: stage before ds_read+MFMA)
    if (kt < 15) stage_tile(c ^ 1, (kt + 1) * 64);

    // B-frags for the whole K-tile (live in regs across all 4 quadrants)
    short8 bk[4][2];
#pragma unroll
    for (int nt = 0; nt < 4; ++nt)
#pragma unroll
      for (int kk = 0; kk < 2; ++kk) {
        int row = wn * 64 + nt * 16 + lr;
        bk[nt][kk] = *(const short8*)&Bsc[row * 64 + (((kk * 4 + lk) ^ (row & 7)) * 8)];
      }

    // software-pipelined quadrants: read q+1's A-frags while q's MFMAs run.
    // afq is statically indexed (full unroll) -> stays in registers (rule #20).
    short8 afq[2][2][2];
#pragma unroll
    for (int mt2 = 0; mt2 < 2; ++mt2)
#pragma unroll
      for (int kk = 0; kk < 2; ++kk) {
        int row = wm * 128 + mt2 * 16 + lr;
        afq[0][mt2][kk] = *(const short8*)&Asc[row * 64 + (((kk * 4 + lk) ^ (row & 7)) * 8)];
      }
#pragma unroll
    for (int q = 0; q < 4; ++q) {
      if (q < 3) {
#pragma unroll
        for (int mt2 = 0; mt2 < 2; ++mt2)
#pragma unroll
          for (int kk = 0; kk < 2; ++kk) {
            int row = wm * 128 + ((q + 1) * 2 + mt2) * 16 + lr;
            afq[(q + 1) & 1][mt2][kk] =
                *(const short8*)&Asc[row * 64 + (((kk * 4 + lk) ^ (row & 7)) * 8)];
          }
      }
      __builtin_amdgcn_s_setprio(1);
#pragma unroll
      for (int mt2 = 0; mt2 < 2; ++mt2)
#pragma unroll
        for (int nt = 0; nt < 4; ++nt)
#pragma unroll
          for (int kk = 0; kk < 2; ++kk)
            acc[q * 2 + mt2][nt] = __builtin_amdgcn_mfma_f32_16x16x32_bf16(
                afq[q & 1][mt2][kk], bk[nt][kk], acc[q * 2 + mt2][nt], 0, 0, 0);
      __builtin_amdgcn_s_setprio(0);
    }

    // single sync point per K-tile. lgkmcnt(0): every ds_read of slot c retired
    // (structural guarantee, not compiler-dependent) before others may overwrite it.
    asm volatile("s_waitcnt vmcnt(0) lgkmcnt(0)" ::: "memory");
    __builtin_amdgcn_s_barrier();
  }

  if (OUT_BF16) {
    // segmented (Q|K|V by nBase>>10; 256-tile never straddles a 1024 boundary),
    // LDS-staged coalesced bf16 stores; two row-half passes (Cs = [128][264])
    const int seg = nBase >> 10;
    const float* bias = seg == 0 ? b0 : (seg == 1 ? b1 : b2);
    s16* outp = (s16*)(seg == 0 ? o0 : (seg == 1 ? o1 : o2));
    const int colL = nBase & 1023;
    s16* Cs = smem;
#pragma unroll
    for (int h = 0; h < 2; ++h) {
      if (wm == h) {
#pragma unroll
        for (int nt = 0; nt < 4; ++nt) {
          int col = wn * 64 + nt * 16 + lr;
          float bb = bias ? bias[colL + col] : 0.0f;
#pragma unroll
          for (int mt = 0; mt < 8; ++mt) {
            int r0 = mt * 16 + lk * 4;
#pragma unroll
            for (int i = 0; i < 4; ++i)
              Cs[(r0 + i) * 264 + col] = f2bf(acc[mt][nt][i] + bb);
          }
        }
      }
      __syncthreads();
      // 128 rows x 256 cols = 4096 short8 slots -> 8 iters of 512 threads
#pragma unroll
      for (int t = 0; t < 8; ++t) {
        int s2 = t * 512 + tid;
        int r = s2 >> 5, g = s2 & 31;
        *(short8*)&outp[(size_t)(mBase + h * 128 + r) * 1024 + colL + g * 8] =
            *(const short8*)&Cs[r * 264 + g * 8];
      }
      __syncthreads();
    }
  } else {
    // f32 direct store (16 lanes x 4 B consecutive = full lines)
    float* outp = (float*)o0;
#pragma unroll
    for (int nt = 0; nt < 4; ++nt) {
      int col = nBase + wn * 64 + nt * 16 + lr;
      float bb = b0[col];
#pragma unroll
      for (int mt = 0; mt < 8; ++mt) {
        int row0 = mBase + wm * 128 + mt * 16 + lk * 4;
#pragma unroll
        for (int i = 0; i < 4; ++i)
          outp[(size_t)(row0 + i) * 1024 + col] = acc[mt][nt][i] + bb;
      }
    }
  }
}

// ---------------- blockwise attention: one workgroup per (b, block, head) ----------------
// qs/ks [128][72] bf16; V stored TRANSPOSED vsT[d][j] (ld=136) with j-group XOR swizzle
// jg ^= (d&7)^(d>>3) -> staging scalar writes ~2-way free, PV B-frags are ds_read_b128.
// Softmax fully in-register (row = 16-lane lr group: 4x shfl_xor); P bf16 overlays qs/ks.
__global__ __launch_bounds__(256) void attn_kernel(const s16* __restrict__ Q, const s16* __restrict__ K,
                                                   const s16* __restrict__ V, s16* __restrict__ O) {
  __shared__ s16   u_qkp[19456];       // qs[128][72] | ks[128][72]; later P[128][152]
  __shared__ s16   vsT[64 * 136];      // 17408 B
  __shared__ float invSum[128];

  const int tid = threadIdx.x;
  const int w = tid >> 6, l = tid & 63;
  const int lr = l & 15, lk = l >> 4;
  const int bid = blockIdx.x;                       // b*512 + n*16 + h
  const int b = bid >> 9;
  const int n = (bid >> 4) & 31;
  const int h = bid & 15;
  const size_t tokBase = (size_t)b * Tt + (size_t)n * BSs;
  const int colBase = h * HDd;

  s16* qs = u_qkp;
  s16* ks = u_qkp + 9216;
  s16* P  = u_qkp;                                  // [128][152]

  // stage Q,K row-major; V transposed+swizzled
#pragma unroll
  for (int t = 0; t < 4; ++t) {
    int s = t * 256 + tid;
    int r = s >> 3, g = s & 7;
    size_t gidx = (tokBase + r) * Cc + colBase + g * 8;
    int4v  dq = *(const int4v*)&Q[gidx];
    int4v  dk = *(const int4v*)&K[gidx];
    short8 dv = *(const short8*)&V[gidx];
    *(int4v*)&qs[r * 72 + g * 8] = dq;
    *(int4v*)&ks[r * 72 + g * 8] = dk;
    int rg = r >> 3, rl = r & 7;
#pragma unroll
    for (int e = 0; e < 8; ++e) {
      int d = g * 8 + e;                            // d&7 == e, d>>3 == g
      vsT[d * 136 + ((rg ^ e ^ g) << 3) + rl] = dv[e];
    }
  }
  __syncthreads();

  // QK^T: wave w owns 32 query rows x 128 key cols = 2x8 16x16 tiles
  f32x4 accS[2][8];
#pragma unroll
  for (int mt = 0; mt < 2; ++mt)
#pragma unroll
    for (int nt = 0; nt < 8; ++nt) accS[mt][nt] = (f32x4){0.f, 0.f, 0.f, 0.f};

#pragma unroll
  for (int st = 0; st < 2; ++st) {
    short8 aq[2], bk[8];
#pragma unroll
    for (int mt = 0; mt < 2; ++mt)
      aq[mt] = *(const short8*)&qs[(w * 32 + mt * 16 + lr) * 72 + st * 32 + lk * 8];
#pragma unroll
    for (int nt = 0; nt < 8; ++nt)
      bk[nt] = *(const short8*)&ks[(nt * 16 + lr) * 72 + st * 32 + lk * 8];
#pragma unroll
    for (int mt = 0; mt < 2; ++mt)
#pragma unroll
      for (int nt = 0; nt < 8; ++nt)
        accS[mt][nt] = __builtin_amdgcn_mfma_f32_16x16x32_bf16(aq[mt], bk[nt], accS[mt][nt], 0, 0, 0);
  }

  // in-register softmax: row (w,mt,lk,i) spread across 16 lanes (lr) x 8 frags (nt).
  // logits = raw/8 -> p = exp((raw - rawmax) * 0.125)
#pragma unroll
  for (int mt = 0; mt < 2; ++mt)
#pragma unroll
    for (int i = 0; i < 4; ++i) {
      float m = accS[mt][0][i];
#pragma unroll
      for (int nt = 1; nt < 8; ++nt) m = fmaxf(m, accS[mt][nt][i]);
      m = fmaxf(m, __shfl_xor(m, 1));
      m = fmaxf(m, __shfl_xor(m, 2));
      m = fmaxf(m, __shfl_xor(m, 4));
      m = fmaxf(m, __shfl_xor(m, 8));
      float sum = 0.f;
#pragma unroll
      for (int nt = 0; nt < 8; ++nt) {
        float p = __expf((accS[mt][nt][i] - m) * 0.125f);
        sum += p;
        accS[mt][nt][i] = p;
      }
      sum += __shfl_xor(sum, 1);
      sum += __shfl_xor(sum, 2);
      sum += __shfl_xor(sum, 4);
      sum += __shfl_xor(sum, 8);
      if (lr == 0) invSum[w * 32 + mt * 16 + lk * 4 + i] = 1.0f / sum;
    }
  __syncthreads();   // all waves done reading qs/ks before P overwrites them

  // P (unnormalized exp) -> LDS bf16
#pragma unroll
  for (int mt = 0; mt < 2; ++mt)
#pragma unroll
    for (int nt = 0; nt < 8; ++nt)
#pragma unroll
      for (int i = 0; i < 4; ++i)
        P[(w * 32 + mt * 16 + lk * 4 + i) * 152 + nt * 16 + lr] = f2bf(accS[mt][nt][i]);
  __syncthreads();

  // O = P * V: all-vector LDS reads now (A from P rows, B from vsT)
  f32x4 accO[2][4];
#pragma unroll
  for (int mt = 0; mt < 2; ++mt)
#pragma unroll
    for (int nt = 0; nt < 4; ++nt) accO[mt][nt] = (f32x4){0.f, 0.f, 0.f, 0.f};

#pragma unroll
  for (int st = 0; st < 4; ++st) {
    short8 ap[2], bv[4];
#pragma unroll
    for (int mt = 0; mt < 2; ++mt)
      ap[mt] = *(const short8*)&P[(w * 32 + mt * 16 + lr) * 152 + st * 32 + lk * 8];
#pragma unroll
    for (int nt = 0; nt < 4; ++nt) {
      int d = nt * 16 + lr;
      bv[nt] = *(const short8*)&vsT[d * 136 + ((((st * 4 + lk) ^ (d & 7) ^ (d >> 3))) << 3)];
    }
#pragma unroll
    for (int mt = 0; mt < 2; ++mt)
#pragma unroll
      for (int nt = 0; nt < 4; ++nt)
        accO[mt][nt] = __builtin_amdgcn_mfma_f32_16x16x32_bf16(ap[mt], bv[nt], accO[mt][nt], 0, 0, 0);
  }

#pragma unroll
  for (int mt = 0; mt < 2; ++mt)
#pragma unroll
    for (int nt = 0; nt < 4; ++nt)
#pragma unroll
      for (int i = 0; i < 4; ++i) {
        int rl = w * 32 + mt * 16 + lk * 4 + i;
        int d = nt * 16 + lr;
        float v = accO[mt][nt][i] * invSum[rl];
        O[(tokBase + rl) * Cc + colBase + d] = f2bf(v);
      }
}

// ---------------- host ----------------
extern "C" void kernel_launch(void* const* d_in, const int* in_sizes, int n_in,
                              void* d_out, int out_size, void* d_ws, size_t ws_size,
                              hipStream_t stream) {
  const float* x  = (const float*)d_in[0];
  const float* Wq = (const float*)d_in[1];
  const float* bq = (const float*)d_in[2];
  const float* Wk = (const float*)d_in[3];
  const float* Wv = (const float*)d_in[4];
  const float* bv = (const float*)d_in[5];
  const float* Wo = (const float*)d_in[6];
  const float* bo = (const float*)d_in[7];

  // ws layout (72 MB): xb 32M | wq|wk|wv (6M contiguous = fused 3072x1024) | wo 2M | Qb 32M.
  // K/V bf16 live in d_out (64 MB), consumed by attn before the final GEMM overwrites it.
  if (ws_size < (size_t)75497472) return;
  char* ws = (char*)d_ws;
  s16* xb  = (s16*)(ws);
  s16* wqb = (s16*)(ws + 33554432);
  s16* wkb = (s16*)(ws + 35651584);
  s16* wvb = (s16*)(ws + 37748736);
  s16* wob = (s16*)(ws + 39845888);
  s16* Qb  = (s16*)(ws + 41943040);
  s16* Kb  = (s16*)((char*)d_out);
  s16* Vb  = (s16*)((char*)d_out + 33554432);

  // 1) convert inputs to bf16
  cvt_x<<<8192, 256, 0, stream>>>(x, xb);
  cvt_w<<<2048, 256, 0, stream>>>(Wq, Wk, Wv, Wo, wqb, wkb, wvb, wob);

  // 2) fused QKV projection: [16384x1024] x [3072x1024]^T -> Qb|Kb|Vb (segmented)
  gemm256<true, 12><<<8 * 8 * 12, 512, 0, stream>>>(xb, wqb, bq, nullptr, bv, Qb, Kb, Vb);

  // 3) blockwise attention; O overwrites Qb (block-disjoint, Q staged to LDS first)
  attn_kernel<<<Bb * NBn * Hh, 256, 0, stream>>>(Qb, Kb, Vb, Qb);

  // 4) out = O Wo^T + bo (f32), overwrites K/V scratch in d_out
  gemm256<false, 4><<<8 * 8 * 4, 512, 0, stream>>>(Qb, wob, bo, bo, bo, (float*)d_out, nullptr, nullptr);
}

// Round 10
// 302.335 us; speedup vs baseline: 1.0603x; 1.0359x over previous
//
#include <hip/hip_runtime.h>
#include <stdint.h>

// Problem: B=4, T=4096, C=1024, H=16, HD=64, NBLOCKS=32, BSIZE=128
#define Bb   4
#define Tt   4096
#define Cc   1024
#define Hh   16
#define HDd  64
#define NBn  32
#define BSs  128
#define MTOT (Bb*Tt)   // 16384 rows

typedef short s16;
typedef __attribute__((ext_vector_type(8))) short  short8;   // 8 bf16 (4 VGPRs)
typedef __attribute__((ext_vector_type(4))) float  f32x4;    // MFMA C/D frag
typedef __attribute__((ext_vector_type(4))) int    int4v;

__device__ __forceinline__ s16 f2bf(float f) {   // f32 -> bf16, RNE
  union { float f; uint32_t u; } c; c.f = f;
  return (s16)((c.u + 0x7fffu + ((c.u >> 16) & 1u)) >> 16);
}

typedef const __attribute__((address_space(1))) void* gas_p;
typedef __attribute__((address_space(3))) void*       las_p;
__device__ __forceinline__ void lds16(const void* g, void* l) {
  // async global->LDS; LDS dest must be wave-uniform (HW adds lane*16)
  __builtin_amdgcn_global_load_lds((gas_p)g, (las_p)l, 16, 0, 0);
}

// ---------------- f32 -> bf16 conversion kernels ----------------
__global__ __launch_bounds__(256) void cvt_x(const float* __restrict__ in, s16* __restrict__ out) {
  int i = blockIdx.x * 256 + threadIdx.x;
  const f32x4* p = (const f32x4*)(in + (size_t)i * 8);
  f32x4 a = p[0], b = p[1];
  short8 o;
  o[0]=f2bf(a[0]); o[1]=f2bf(a[1]); o[2]=f2bf(a[2]); o[3]=f2bf(a[3]);
  o[4]=f2bf(b[0]); o[5]=f2bf(b[1]); o[6]=f2bf(b[2]); o[7]=f2bf(b[3]);
  *(short8*)(out + (size_t)i * 8) = o;
}

__global__ __launch_bounds__(256) void cvt_w(const float* w0, const float* w1,
                                             const float* w2, const float* w3,
                                             s16* o0, s16* o1, s16* o2, s16* o3) {
  int i = blockIdx.x * 256 + threadIdx.x;
  int which = i >> 17;
  int j = i & 131071;
  const float* w = which == 0 ? w0 : which == 1 ? w1 : which == 2 ? w2 : w3;
  s16*         o = which == 0 ? o0 : which == 1 ? o1 : which == 2 ? o2 : o3;
  const f32x4* p = (const f32x4*)(w + (size_t)j * 8);
  f32x4 a = p[0], b = p[1];
  short8 v;
  v[0]=f2bf(a[0]); v[1]=f2bf(a[1]); v[2]=f2bf(a[2]); v[3]=f2bf(a[3]);
  v[4]=f2bf(b[0]); v[5]=f2bf(b[1]); v[6]=f2bf(b[2]); v[7]=f2bf(b[3]);
  *(short8*)(o + (size_t)j * 8) = v;
}

// ---------------- 256x256 bt-GEMM, counted-vmcnt 4-phase pipeline ----------------
// 8 waves (2m x 4n), per-wave 128x64 out = 8x4 16x16 frags. BK=64, 16 K-tiles,
// 2-slot LDS dbuf (128 KiB). Staging of tile kt+1 split into 4 units, one per phase:
//   u0 = B rows 0-127 (2 loads/thread)      issued phase 0
//   u1 = B rows 128-255 (2)                 issued phase 1
//   u2 = A rows {0-63, 128-191} (2)         issued phase 2
//   u3 = A rows {64-127, 192-255} (2)       issued phase 3
// Reads (tile kt): phase0 = all B + A-quad0 (rows wm*128+[0,32) - in u2 units of kt);
// phase1 = A-quad1 (rows +[32,64) - u2); phase2 = quad2 ([64,96) - u3); phase3 = quad3 (u3).
// FIFO-vmcnt proof of the two counted waits (per-wave wait + s_barrier globalizes):
//  - boundary into kt: outstanding = u0..u3(kt) (8, issued during kt-1).  vmcnt(2)
//    retires the 6 oldest = u0,u1,u2(kt) -> phase0/1 reads safe; u3(kt) stays in flight.
//  - phase 2 of kt: outstanding = u3(kt) + u0,u1(kt+1) = 6.  vmcnt(4) retires the 2
//    oldest = u3(kt) -> quad2/3 reads safe.  (kt==15 stages nothing: vmcnt(0) there.)
// Queue holds 2-8 loads at ALL times -> no drain stall (T4, m218). lgkmcnt(0) only at
// the boundary (slot handoff: my slot-c^1 ds_reads must retire before others restage
// it; rule #18 - structural, not compiler-dependent).
// LDS element (row,k) at [row*64 + ((k>>3)^(row&7))*8 + (k&7)]; swizzle applied on
// the global src (global_load_lds dest must stay linear). 0 bank conflicts (r6-r9).
template <bool OUT_BF16, int NXT>
__global__ __launch_bounds__(512, 2) void gemm256(const s16* __restrict__ Ag, const s16* __restrict__ Bg,
                                                  const float* b0, const float* b1, const float* b2,
                                                  void* o0, void* o1, void* o2) {
  __shared__ s16 smem[65536];   // 128 KiB: As[2][256][64] | Bs[2][256][64]

  const int tid = threadIdx.x;
  const int w = tid >> 6, l = tid & 63;
  const int lr = l & 15, lk = l >> 4;
  const int wm = w >> 2, wn = w & 3;

  // XCD-chunked block swizzle: xcd owns 8 m-tiles x NXT n-tiles (grid = 8*8*NXT)
  const int lid = blockIdx.x;
  const int xcd = lid & 7, s0 = lid >> 3;
  const int my = xcd * 8 + s0 / NXT;
  const int nx = s0 - (s0 / NXT) * NXT;
  const int mBase = my * 256, nBase = nx * 256;

  f32x4 acc[8][4];
#pragma unroll
  for (int i = 0; i < 8; ++i)
#pragma unroll
    for (int j = 0; j < 4; ++j) acc[i][j] = (f32x4){0.f, 0.f, 0.f, 0.f};

  // 2 loads/thread covering 128 rows starting at rowOff (tile-local, mult of 64)
  auto stage_pair = [&](s16* lbase, const s16* gbase, int gRowBase, int rowOff, int k0) {
#pragma unroll
    for (int j = 0; j < 2; ++j) {
      int s = j * 512 + tid;
      int r = s >> 3;                               // 0..127 local
      int kg = (s & 7) ^ (r & 7);
      lds16(gbase + (size_t)(gRowBase + rowOff + r) * Cc + (k0 + kg * 8),
            lbase + rowOff * 64 + (j * 512 + (tid & ~63)) * 8);
    }
  };
  // 1 load/thread covering 64 rows starting at rowOff
  auto stage_one = [&](s16* lbase, const s16* gbase, int gRowBase, int rowOff, int k0) {
    int r = tid >> 3;
    int kg = (tid & 7) ^ (r & 7);
    lds16(gbase + (size_t)(gRowBase + rowOff + r) * Cc + (k0 + kg * 8),
          lbase + rowOff * 64 + (tid & ~63) * 8);
  };

  auto rdquad = [&](short8 (&dst)[2][2], int q, const s16* Asrc) {
#pragma unroll
    for (int mt2 = 0; mt2 < 2; ++mt2)
#pragma unroll
      for (int kk = 0; kk < 2; ++kk) {
        int row = wm * 128 + (q * 2 + mt2) * 16 + lr;
        dst[mt2][kk] = *(const short8*)&Asrc[row * 64 + (((kk * 4 + lk) ^ (row & 7)) * 8)];
      }
  };
  auto mfmaq = [&](int q, short8 (&src)[2][2], short8 (&bkk)[4][2]) {
    __builtin_amdgcn_s_setprio(1);
#pragma unroll
    for (int mt2 = 0; mt2 < 2; ++mt2)
#pragma unroll
      for (int nt = 0; nt < 4; ++nt)
#pragma unroll
        for (int kk = 0; kk < 2; ++kk)
          acc[q * 2 + mt2][nt] = __builtin_amdgcn_mfma_f32_16x16x32_bf16(
              src[mt2][kk], bkk[nt][kk], acc[q * 2 + mt2][nt], 0, 0, 0);
    __builtin_amdgcn_s_setprio(0);
  };

  // prologue: stage tile 0 -> slot 0, same per-thread FIFO order as steady state
  {
    s16* Asl = smem;
    s16* Bsl = smem + 32768;
    stage_pair(Bsl, Bg, nBase, 0, 0);       // u0
    stage_pair(Bsl, Bg, nBase, 128, 0);     // u1
    stage_one(Asl, Ag, mBase, 0, 0);        // u2a
    stage_one(Asl, Ag, mBase, 128, 0);      // u2b
    stage_one(Asl, Ag, mBase, 64, 0);       // u3a
    stage_one(Asl, Ag, mBase, 192, 0);      // u3b
  }

  for (int kt = 0; kt < 16; ++kt) {
    const int c = kt & 1;
    const s16* Asc = smem + c * 16384;
    const s16* Bsc = smem + 32768 + c * 16384;
    s16* Asl = smem + (c ^ 1) * 16384;
    s16* Bsl = smem + 32768 + (c ^ 1) * 16384;
    const int k1 = (kt + 1) * 64;
    const bool pf = (kt < 15);

    // ---- tile boundary: counted wait, never a full drain ----
    asm volatile("s_waitcnt lgkmcnt(0)" ::: "memory");
    asm volatile("s_waitcnt vmcnt(2)" ::: "memory");
    __builtin_amdgcn_s_barrier();

    // ---- phase 0 ----
    if (pf) stage_pair(Bsl, Bg, nBase, 0, k1);                 // u0(kt+1)
    short8 bk[4][2];
#pragma unroll
    for (int nt = 0; nt < 4; ++nt)
#pragma unroll
      for (int kk = 0; kk < 2; ++kk) {
        int row = wn * 64 + nt * 16 + lr;
        bk[nt][kk] = *(const short8*)&Bsc[row * 64 + (((kk * 4 + lk) ^ (row & 7)) * 8)];
      }
    short8 afA[2][2], afB[2][2];
    rdquad(afA, 0, Asc);
    rdquad(afB, 1, Asc);          // prefetch quad1 (same u2 units - safe)
    mfmaq(0, afA, bk);

    // ---- phase 1 ----
    if (pf) stage_pair(Bsl, Bg, nBase, 128, k1);               // u1(kt+1)
    mfmaq(1, afB, bk);

    // ---- phase 2: second counted wait (u3(kt) deadline) ----
    if (pf) asm volatile("s_waitcnt vmcnt(4)" ::: "memory");
    else    asm volatile("s_waitcnt vmcnt(0)" ::: "memory");
    __builtin_amdgcn_s_barrier();
    if (pf) { stage_one(Asl, Ag, mBase, 0, k1); stage_one(Asl, Ag, mBase, 128, k1); }  // u2(kt+1)
    rdquad(afA, 2, Asc);
    rdquad(afB, 3, Asc);          // prefetch quad3 (same u3 units - safe)
    mfmaq(2, afA, bk);

    // ---- phase 3 ----
    if (pf) { stage_one(Asl, Ag, mBase, 64, k1); stage_one(Asl, Ag, mBase, 192, k1); } // u3(kt+1)
    mfmaq(3, afB, bk);
  }

  if (OUT_BF16) {
    __syncthreads();   // all waves' loop reads retired before Cs overlays smem
    // segmented (Q|K|V by nBase>>10; 256-tile never straddles a 1024 boundary),
    // LDS-staged coalesced bf16 stores; two row-half passes (Cs = [128][264])
    const int seg = nBase >> 10;
    const float* bias = seg == 0 ? b0 : (seg == 1 ? b1 : b2);
    s16* outp = (s16*)(seg == 0 ? o0 : (seg == 1 ? o1 : o2));
    const int colL = nBase & 1023;
    s16* Cs = smem;
#pragma unroll
    for (int h = 0; h < 2; ++h) {
      if (wm == h) {
#pragma unroll
        for (int nt = 0; nt < 4; ++nt) {
          int col = wn * 64 + nt * 16 + lr;
          float bb = bias ? bias[colL + col] : 0.0f;
#pragma unroll
          for (int mt = 0; mt < 8; ++mt) {
            int r0 = mt * 16 + lk * 4;
#pragma unroll
            for (int i = 0; i < 4; ++i)
              Cs[(r0 + i) * 264 + col] = f2bf(acc[mt][nt][i] + bb);
          }
        }
      }
      __syncthreads();
      // 128 rows x 256 cols = 4096 short8 slots -> 8 iters of 512 threads
#pragma unroll
      for (int t = 0; t < 8; ++t) {
        int s2 = t * 512 + tid;
        int r = s2 >> 5, g = s2 & 31;
        *(short8*)&outp[(size_t)(mBase + h * 128 + r) * 1024 + colL + g * 8] =
            *(const short8*)&Cs[r * 264 + g * 8];
      }
      __syncthreads();
    }
  } else {
    // f32 direct store (16 lanes x 4 B consecutive = full lines); no LDS reuse
    float* outp = (float*)o0;
#pragma unroll
    for (int nt = 0; nt < 4; ++nt) {
      int col = nBase + wn * 64 + nt * 16 + lr;
      float bb = b0[col];
#pragma unroll
      for (int mt = 0; mt < 8; ++mt) {
        int row0 = mBase + wm * 128 + mt * 16 + lk * 4;
#pragma unroll
        for (int i = 0; i < 4; ++i)
          outp[(size_t)(row0 + i) * 1024 + col] = acc[mt][nt][i] + bb;
      }
    }
  }
}

// ---------------- blockwise attention: one workgroup per (b, block, head) ----------------
// qs/ks [128][72] bf16; V stored TRANSPOSED vsT[d][j] (ld=136) with j-group XOR swizzle
// jg ^= (d&7)^(d>>3) -> staging scalar writes ~2-way free, PV B-frags are ds_read_b128.
// Softmax fully in-register (row = 16-lane lr group: 4x shfl_xor); P bf16 overlays qs/ks.
__global__ __launch_bounds__(256) void attn_kernel(const s16* __restrict__ Q, const s16* __restrict__ K,
                                                   const s16* __restrict__ V, s16* __restrict__ O) {
  __shared__ s16   u_qkp[19456];       // qs[128][72] | ks[128][72]; later P[128][152]
  __shared__ s16   vsT[64 * 136];      // 17408 B
  __shared__ float invSum[128];

  const int tid = threadIdx.x;
  const int w = tid >> 6, l = tid & 63;
  const int lr = l & 15, lk = l >> 4;
  const int bid = blockIdx.x;                       // b*512 + n*16 + h
  const int b = bid >> 9;
  const int n = (bid >> 4) & 31;
  const int h = bid & 15;
  const size_t tokBase = (size_t)b * Tt + (size_t)n * BSs;
  const int colBase = h * HDd;

  s16* qs = u_qkp;
  s16* ks = u_qkp + 9216;
  s16* P  = u_qkp;                                  // [128][152]

  // stage Q,K row-major; V transposed+swizzled
#pragma unroll
  for (int t = 0; t < 4; ++t) {
    int s = t * 256 + tid;
    int r = s >> 3, g = s & 7;
    size_t gidx = (tokBase + r) * Cc + colBase + g * 8;
    int4v  dq = *(const int4v*)&Q[gidx];
    int4v  dk = *(const int4v*)&K[gidx];
    short8 dv = *(const short8*)&V[gidx];
    *(int4v*)&qs[r * 72 + g * 8] = dq;
    *(int4v*)&ks[r * 72 + g * 8] = dk;
    int rg = r >> 3, rl = r & 7;
#pragma unroll
    for (int e = 0; e < 8; ++e) {
      int d = g * 8 + e;                            // d&7 == e, d>>3 == g
      vsT[d * 136 + ((rg ^ e ^ g) << 3) + rl] = dv[e];
    }
  }
  __syncthreads();

  // QK^T: wave w owns 32 query rows x 128 key cols = 2x8 16x16 tiles
  f32x4 accS[2][8];
#pragma unroll
  for (int mt = 0; mt < 2; ++mt)
#pragma unroll
    for (int nt = 0; nt < 8; ++nt) accS[mt][nt] = (f32x4){0.f, 0.f, 0.f, 0.f};

#pragma unroll
  for (int st = 0; st < 2; ++st) {
    short8 aq[2], bk[8];
#pragma unroll
    for (int mt = 0; mt < 2; ++mt)
      aq[mt] = *(const short8*)&qs[(w * 32 + mt * 16 + lr) * 72 + st * 32 + lk * 8];
#pragma unroll
    for (int nt = 0; nt < 8; ++nt)
      bk[nt] = *(const short8*)&ks[(nt * 16 + lr) * 72 + st * 32 + lk * 8];
#pragma unroll
    for (int mt = 0; mt < 2; ++mt)
#pragma unroll
      for (int nt = 0; nt < 8; ++nt)
        accS[mt][nt] = __builtin_amdgcn_mfma_f32_16x16x32_bf16(aq[mt], bk[nt], accS[mt][nt], 0, 0, 0);
  }

  // in-register softmax: row (w,mt,lk,i) spread across 16 lanes (lr) x 8 frags (nt).
  // logits = raw/8 -> p = exp((raw - rawmax) * 0.125)
#pragma unroll
  for (int mt = 0; mt < 2; ++mt)
#pragma unroll
    for (int i = 0; i < 4; ++i) {
      float m = accS[mt][0][i];
#pragma unroll
      for (int nt = 1; nt < 8; ++nt) m = fmaxf(m, accS[mt][nt][i]);
      m = fmaxf(m, __shfl_xor(m, 1));
      m = fmaxf(m, __shfl_xor(m, 2));
      m = fmaxf(m, __shfl_xor(m, 4));
      m = fmaxf(m, __shfl_xor(m, 8));
      float sum = 0.f;
#pragma unroll
      for (int nt = 0; nt < 8; ++nt) {
        float p = __expf((accS[mt][nt][i] - m) * 0.125f);
        sum += p;
        accS[mt][nt][i] = p;
      }
      sum += __shfl_xor(sum, 1);
      sum += __shfl_xor(sum, 2);
      sum += __shfl_xor(sum, 4);
      sum += __shfl_xor(sum, 8);
      if (lr == 0) invSum[w * 32 + mt * 16 + lk * 4 + i] = 1.0f / sum;
    }
  __syncthreads();   // all waves done reading qs/ks before P overwrites them

  // P (unnormalized exp) -> LDS bf16
#pragma unroll
  for (int mt = 0; mt < 2; ++mt)
#pragma unroll
    for (int nt = 0; nt < 8; ++nt)
#pragma unroll
      for (int i = 0; i < 4; ++i)
        P[(w * 32 + mt * 16 + lk * 4 + i) * 152 + nt * 16 + lr] = f2bf(accS[mt][nt][i]);
  __syncthreads();

  // O = P * V: all-vector LDS reads now (A from P rows, B from vsT)
  f32x4 accO[2][4];
#pragma unroll
  for (int mt = 0; mt < 2; ++mt)
#pragma unroll
    for (int nt = 0; nt < 4; ++nt) accO[mt][nt] = (f32x4){0.f, 0.f, 0.f, 0.f};

#pragma unroll
  for (int st = 0; st < 4; ++st) {
    short8 ap[2], bv[4];
#pragma unroll
    for (int mt = 0; mt < 2; ++mt)
      ap[mt] = *(const short8*)&P[(w * 32 + mt * 16 + lr) * 152 + st * 32 + lk * 8];
#pragma unroll
    for (int nt = 0; nt < 4; ++nt) {
      int d = nt * 16 + lr;
      bv[nt] = *(const short8*)&vsT[d * 136 + ((((st * 4 + lk) ^ (d & 7) ^ (d >> 3))) << 3)];
    }
#pragma unroll
    for (int mt = 0; mt < 2; ++mt)
#pragma unroll
      for (int nt = 0; nt < 4; ++nt)
        accO[mt][nt] = __builtin_amdgcn_mfma_f32_16x16x32_bf16(ap[mt], bv[nt], accO[mt][nt], 0, 0, 0);
  }

#pragma unroll
  for (int mt = 0; mt < 2; ++mt)
#pragma unroll
    for (int nt = 0; nt < 4; ++nt)
#pragma unroll
      for (int i = 0; i < 4; ++i) {
        int rl = w * 32 + mt * 16 + lk * 4 + i;
        int d = nt * 16 + lr;
        float v = accO[mt][nt][i] * invSum[rl];
        O[(tokBase + rl) * Cc + colBase + d] = f2bf(v);
      }
}

// ---------------- host ----------------
extern "C" void kernel_launch(void* const* d_in, const int* in_sizes, int n_in,
                              void* d_out, int out_size, void* d_ws, size_t ws_size,
                              hipStream_t stream) {
  const float* x  = (const float*)d_in[0];
  const float* Wq = (const float*)d_in[1];
  const float* bq = (const float*)d_in[2];
  const float* Wk = (const float*)d_in[3];
  const float* Wv = (const float*)d_in[4];
  const float* bv = (const float*)d_in[5];
  const float* Wo = (const float*)d_in[6];
  const float* bo = (const float*)d_in[7];

  // ws layout (72 MB): xb 32M | wq|wk|wv (6M contiguous = fused 3072x1024) | wo 2M | Qb 32M.
  // K/V bf16 live in d_out (64 MB), consumed by attn before the final GEMM overwrites it.
  if (ws_size < (size_t)75497472) return;
  char* ws = (char*)d_ws;
  s16* xb  = (s16*)(ws);
  s16* wqb = (s16*)(ws + 33554432);
  s16* wkb = (s16*)(ws + 35651584);
  s16* wvb = (s16*)(ws + 37748736);
  s16* wob = (s16*)(ws + 39845888);
  s16* Qb  = (s16*)(ws + 41943040);
  s16* Kb  = (s16*)((char*)d_out);
  s16* Vb  = (s16*)((char*)d_out + 33554432);

  // 1) convert inputs to bf16
  cvt_x<<<8192, 256, 0, stream>>>(x, xb);
  cvt_w<<<2048, 256, 0, stream>>>(Wq, Wk, Wv, Wo, wqb, wkb, wvb, wob);

  // 2) fused QKV projection: [16384x1024] x [3072x1024]^T -> Qb|Kb|Vb (segmented)
  gemm256<true, 12><<<8 * 8 * 12, 512, 0, stream>>>(xb, wqb, bq, nullptr, bv, Qb, Kb, Vb);

  // 3) blockwise attention; O overwrites Qb (block-disjoint, Q staged to LDS first)
  attn_kernel<<<Bb * NBn * Hh, 256, 0, stream>>>(Qb, Kb, Vb, Qb);

  // 4) out = O Wo^T + bo (f32), overwrites K/V scratch in d_out
  gemm256<false, 4><<<8 * 8 * 4, 512, 0, stream>>>(Qb, wob, bo, bo, bo, (float*)d_out, nullptr, nullptr);
}